// Round 2
// baseline (733.126 us; speedup 1.0000x reference)
//
#include <hip/hip_runtime.h>

// MiniSTU: out[b,l,o] = sum_k sum_{s<=l} phi[l-s,k] * (x[b,s,:]@Mp[k])[o]
//                     + sum_k sum_{s<=l} (-1)^(l-s) phi[l-s,k] * (x[b,s,:]@Mm[k])[o]
// Stage 1: Z[kk][o][s] = (x[b] @ M[kk])^T  (48 = 24 filters x 2 signs), bf16
// Stage 2: out[b,l,o] = sum_kk sum_s phiB[kk][l-s] * Z[kk][o][s]  (Toeplitz MFMA GEMM)

#define L_ 1024
#define KK_ 48
#define KG_ 12   // split-K groups for stage 2 (4 kk each)

typedef __attribute__((ext_vector_type(8))) short bf16x8;
typedef __attribute__((ext_vector_type(4))) float f32x4;

__device__ inline unsigned short f2bf(float f) {
    unsigned u = __float_as_uint(f);
    u += 0x7FFFu + ((u >> 16) & 1u);   // RNE
    return (unsigned short)(u >> 16);
}

// ---- prep: x (f32) -> xb (bf16), 1,048,576 elems, 4/thread -------------------
__global__ void k_prep_x(const float* __restrict__ x, unsigned short* __restrict__ xb) {
    int i = (blockIdx.x * 256 + threadIdx.x) * 4;
    float4 v = *(const float4*)(x + i);
    ushort4 o;
    o.x = f2bf(v.x); o.y = f2bf(v.y); o.z = f2bf(v.z); o.w = f2bf(v.w);
    *(ushort4*)(xb + i) = o;
}

// ---- prep: phiB[kk][t] = phi[t][k] * ((kk>=24 && t odd) ? -1 : 1), bf16 ------
__global__ void k_prep_phi(const float* __restrict__ phi, unsigned short* __restrict__ phiB) {
    int kk = blockIdx.x;
    int k = (kk < 24) ? kk : kk - 24;
    for (int it = 0; it < 4; ++it) {
        int t = it * 256 + threadIdx.x;
        float v = phi[t * 24 + k];
        if (kk >= 24 && (t & 1)) v = -v;
        phiB[kk * 1024 + t] = f2bf(v);
    }
}

// ---- prep: MbT[kk][o][i] = M(kk)[i][o] (bf16), tiled transpose ---------------
__global__ void k_transpose_M(const float* __restrict__ Mp, const float* __restrict__ Mm,
                              unsigned short* __restrict__ MbT) {
    __shared__ float tile[32][33];
    int kk = blockIdx.z;
    const float* src = ((kk < 24) ? Mp : Mm) + (size_t)((kk < 24) ? kk : kk - 24) * 65536;
    int i0 = blockIdx.x * 32, o0 = blockIdx.y * 32;
    int tx = threadIdx.x, ty = threadIdx.y;
    for (int j = 0; j < 4; ++j)
        tile[ty + j * 8][tx] = src[(i0 + ty + j * 8) * 256 + o0 + tx];
    __syncthreads();
    for (int j = 0; j < 4; ++j)
        MbT[(size_t)kk * 65536 + (o0 + ty + j * 8) * 256 + i0 + tx] = f2bf(tile[tx][ty + j * 8]);
}

// ---- stage 1: per b. grid (8 m-tiles, 96 n-tiles = 48kk x 2 o-halves), 256 thr
// D[s][o-chunk] = xb[b] (1024x256) @ MbT[kk]^T-chunk; write Z[kk][o][s] bf16.
__global__ __launch_bounds__(256) void k_stage1(const unsigned short* __restrict__ xb_b,
                                                const unsigned short* __restrict__ MbT,
                                                unsigned short* __restrict__ Z) {
    __shared__ unsigned short Al[128 * 40];  // [128 s][32 i] pad->40
    __shared__ unsigned short Bl[128 * 40];  // [128 o][32 i] pad->40
    int tid = threadIdx.x, lane = tid & 63, w = tid >> 6;
    int wm = w >> 1, wn = w & 1;
    int m0 = blockIdx.x * 128;
    int kk = blockIdx.y >> 1;
    int o0 = (blockIdx.y & 1) * 128;
    const unsigned short* Bsrc = MbT + (size_t)kk * 65536;
    int l16 = lane & 15, kofs = (lane >> 4) * 8;

    f32x4 acc[4][4];
    for (int i = 0; i < 4; ++i)
        for (int j = 0; j < 4; ++j) {
            acc[i][j][0] = 0.f; acc[i][j][1] = 0.f; acc[i][j][2] = 0.f; acc[i][j][3] = 0.f;
        }

    // each thread covers 16 contiguous i-elems (two uint4) of one row per K-tile:
    // full 128 rows x 32 i per buffer.
    int row = tid >> 1, half = tid & 1;
    const unsigned short* asrc = xb_b + (m0 + row) * 256 + half * 16;
    const unsigned short* bsrc = Bsrc + (o0 + row) * 256 + half * 16;
    uint4 va0 = *(const uint4*)(asrc);
    uint4 va1 = *(const uint4*)(asrc + 8);
    uint4 vb0 = *(const uint4*)(bsrc);
    uint4 vb1 = *(const uint4*)(bsrc + 8);

    for (int ko = 0; ko < 8; ++ko) {
        __syncthreads();
        *(uint4*)(Al + row * 40 + half * 16)     = va0;
        *(uint4*)(Al + row * 40 + half * 16 + 8) = va1;
        *(uint4*)(Bl + row * 40 + half * 16)     = vb0;
        *(uint4*)(Bl + row * 40 + half * 16 + 8) = vb1;
        __syncthreads();
        if (ko < 7) {  // prefetch next K-tile
            va0 = *(const uint4*)(asrc + (ko + 1) * 32);
            va1 = *(const uint4*)(asrc + (ko + 1) * 32 + 8);
            vb0 = *(const uint4*)(bsrc + (ko + 1) * 32);
            vb1 = *(const uint4*)(bsrc + (ko + 1) * 32 + 8);
        }
        bf16x8 af[4], bfv[4];
        for (int mi = 0; mi < 4; ++mi)
            af[mi] = *(const bf16x8*)(Al + (wm * 64 + mi * 16 + l16) * 40 + kofs);
        for (int ni = 0; ni < 4; ++ni)
            bfv[ni] = *(const bf16x8*)(Bl + (wn * 64 + ni * 16 + l16) * 40 + kofs);
        for (int mi = 0; mi < 4; ++mi)
            for (int ni = 0; ni < 4; ++ni)
                acc[mi][ni] = __builtin_amdgcn_mfma_f32_16x16x32_bf16(af[mi], bfv[ni], acc[mi][ni], 0, 0, 0);
    }

    // epilogue: D rows=(lane>>4)*4+j (s), col=lane&15 (o); store transposed Z[kk][o][s]
    int r4 = (lane >> 4) * 4;
    for (int mi = 0; mi < 4; ++mi) {
        int sbase = m0 + wm * 64 + mi * 16 + r4;
        for (int ni = 0; ni < 4; ++ni) {
            int o = o0 + wn * 64 + ni * 16 + l16;
            ushort4 pk;
            pk.x = f2bf(acc[mi][ni][0]); pk.y = f2bf(acc[mi][ni][1]);
            pk.z = f2bf(acc[mi][ni][2]); pk.w = f2bf(acc[mi][ni][3]);
            *(ushort4*)(Z + (size_t)kk * 262144 + (size_t)o * 1024 + sbase) = pk;
        }
    }
}

// ---- stage 2: per b. grid (16 l-tiles(64), 2 o-tiles(128), 12 kk-groups), 256 thr
// partial[kg][l][o] = sum_{kk in group} sum_s phiB[kk][l-s] * Z[kk][o][s]
__global__ __launch_bounds__(256) void k_stage2(const unsigned short* __restrict__ Z,
                                                const unsigned short* __restrict__ phiB,
                                                float* __restrict__ partial) {
    __shared__ unsigned short Al[64 * 72];   // Toeplitz [64 l][64 s] pad->72
    __shared__ unsigned short Zl[128 * 72];  // [128 o][64 s] pad->72
    __shared__ unsigned short Sl[1024];      // filter strip for current kk
    int tid = threadIdx.x, lane = tid & 63, w = tid >> 6;
    int wm = w >> 1, wn = w & 1;
    int lb = blockIdx.x, l0 = lb * 64;
    int o0 = blockIdx.y * 128;
    int kg = blockIdx.z;
    int l16 = lane & 15, kofs = (lane >> 4) * 8;

    f32x4 acc[2][4];
    for (int i = 0; i < 2; ++i)
        for (int j = 0; j < 4; ++j) {
            acc[i][j][0] = 0.f; acc[i][j][1] = 0.f; acc[i][j][2] = 0.f; acc[i][j][3] = 0.f;
        }

    for (int kkx = 0; kkx < 4; ++kkx) {
        int kk = kg * 4 + kkx;
        const unsigned short* Zkk = Z + (size_t)kk * 262144;
        __syncthreads();  // protect Sl/Al/Zl from previous iteration readers
        ((unsigned int*)Sl)[tid] = ((const unsigned int*)(phiB + kk * 1024))[tid];
        ((unsigned int*)Sl)[256 + tid] = ((const unsigned int*)(phiB + kk * 1024))[256 + tid];
        for (int sc = 0; sc <= lb; ++sc) {  // causal: s-blocks 0..lb
            int s0 = sc * 64;
            // prefetch Z tile into regs (latency overlaps barrier + A-build)
            uint4 zv[4];
#pragma unroll
            for (int it = 0; it < 4; ++it) {
                int c = it * 256 + tid, orow = c >> 3, co = (c & 7) * 8;
                zv[it] = *(const uint4*)(Zkk + (size_t)(o0 + orow) * 1024 + s0 + co);
            }
            __syncthreads();
            // build Toeplitz A tile: A[l'][s'] = phiB[kk][(l0+l')-(s0+s')] (0 if <0)
#pragma unroll
            for (int it = 0; it < 8; ++it) {
                int p = it * 512 + tid * 2;
                int lr = p >> 6, sr = p & 63;
                int t0 = (l0 + lr) - (s0 + sr);
                unsigned v0 = (t0 >= 0) ? (unsigned)Sl[t0] : 0u;
                unsigned v1 = (t0 >= 1) ? (unsigned)Sl[t0 - 1] : 0u;
                *(unsigned int*)(Al + lr * 72 + sr) = v0 | (v1 << 16);
            }
#pragma unroll
            for (int it = 0; it < 4; ++it) {
                int c = it * 256 + tid, orow = c >> 3, co = (c & 7) * 8;
                *(uint4*)(Zl + orow * 72 + co) = zv[it];
            }
            __syncthreads();
#pragma unroll
            for (int ks = 0; ks < 2; ++ks) {
                int ko = ks * 32 + kofs;
                bf16x8 af[2], bfv[4];
                for (int mi = 0; mi < 2; ++mi)
                    af[mi] = *(const bf16x8*)(Al + (wm * 32 + mi * 16 + l16) * 72 + ko);
                for (int ni = 0; ni < 4; ++ni)
                    bfv[ni] = *(const bf16x8*)(Zl + (wn * 64 + ni * 16 + l16) * 72 + ko);
                for (int mi = 0; mi < 2; ++mi)
                    for (int ni = 0; ni < 4; ++ni)
                        acc[mi][ni] = __builtin_amdgcn_mfma_f32_16x16x32_bf16(af[mi], bfv[ni], acc[mi][ni], 0, 0, 0);
            }
        }
    }

    int r4 = (lane >> 4) * 4;
    for (int mi = 0; mi < 2; ++mi) {
        int l = l0 + wm * 32 + mi * 16 + r4;
        for (int ni = 0; ni < 4; ++ni) {
            int o = o0 + wn * 64 + ni * 16 + l16;
            float* dst = partial + (size_t)kg * 262144 + (size_t)l * 256 + o;
            dst[0]   = acc[mi][ni][0];
            dst[256] = acc[mi][ni][1];
            dst[512] = acc[mi][ni][2];
            dst[768] = acc[mi][ni][3];
        }
    }
}

// ---- reduce: out[b][l][o] = sum_kg partial[kg][l][o] -------------------------
__global__ void k_reduce(const float* __restrict__ partial, float* __restrict__ outb) {
    int i = (blockIdx.x * 256 + threadIdx.x) * 4;
    float4 s = *(const float4*)(partial + i);
#pragma unroll
    for (int kg = 1; kg < KG_; ++kg) {
        float4 v = *(const float4*)(partial + (size_t)kg * 262144 + i);
        s.x += v.x; s.y += v.y; s.z += v.z; s.w += v.w;
    }
    *(float4*)(outb + i) = s;
}

extern "C" void kernel_launch(void* const* d_in, const int* in_sizes, int n_in,
                              void* d_out, int out_size, void* d_ws, size_t ws_size,
                              hipStream_t stream) {
    const float* x   = (const float*)d_in[0];   // [4,1024,256]
    const float* phi = (const float*)d_in[1];   // [1024,24]
    const float* Mp  = (const float*)d_in[2];   // [24,256,256]
    const float* Mm  = (const float*)d_in[3];   // [24,256,256]
    float* out = (float*)d_out;                 // [4,1024,256]

    char* ws = (char*)d_ws;
    unsigned short* xb      = (unsigned short*)(ws);                // 2,097,152 B
    unsigned short* phiB    = (unsigned short*)(ws + 2097152);      //    98,304 B
    unsigned short* MbT     = (unsigned short*)(ws + 2195456);      // 6,291,456 B
    unsigned short* Z       = (unsigned short*)(ws + 8486912);      // 25,165,824 B (one batch)
    float*          partial = (float*)(ws + 33652736);              // 12,582,912 B  -> total ~44.1 MB

    k_prep_x<<<dim3(1024), dim3(256), 0, stream>>>(x, xb);
    k_prep_phi<<<dim3(48), dim3(256), 0, stream>>>(phi, phiB);
    k_transpose_M<<<dim3(8, 8, 48), dim3(32, 8), 0, stream>>>(Mp, Mm, MbT);

    for (int b = 0; b < 4; ++b) {
        k_stage1<<<dim3(8, 96), dim3(256), 0, stream>>>(xb + (size_t)b * 262144, MbT, Z);
        k_stage2<<<dim3(16, 2, KG_), dim3(256), 0, stream>>>(Z, phiB, partial);
        k_reduce<<<dim3(256), dim3(256), 0, stream>>>(partial, out + (size_t)b * 262144);
    }
}

// Round 3
// 430.147 us; speedup vs baseline: 1.7044x; 1.7044x over previous
//
#include <hip/hip_runtime.h>

// MiniSTU: out[b,l,o] = sum_k sum_{s<=l} phi[l-s,k]*(x@Mp[k])[o] + (-1)^(l-s)-weighted Mm term
// Stage 1: Z[b][kk][o][s] = (x[b] @ M[kk])^T   (48 = 24 filters x 2 signs), bf16
// Stage 2: partial[b][kg][l][o] = sum_{kk in kg} sum_s ToepA[kk][lb-sc][l'][s'] * Z[b][kk][o][s]
// Reduce:  out = sum_kg partial

#define ZB_ 12582912  // Z elems per batch (48*256*1024)

typedef __attribute__((ext_vector_type(8))) short bf16x8;
typedef __attribute__((ext_vector_type(4))) float f32x4;

__device__ inline unsigned short f2bf(float f) {
    unsigned u = __float_as_uint(f);
    u += 0x7FFFu + ((u >> 16) & 1u);   // RNE
    return (unsigned short)(u >> 16);
}

// ---- prep: x (f32) -> xb (bf16) ---------------------------------------------
__global__ void k_prep_x(const float* __restrict__ x, unsigned short* __restrict__ xb) {
    int i = (blockIdx.x * 256 + threadIdx.x) * 4;
    float4 v = *(const float4*)(x + i);
    ushort4 o;
    o.x = f2bf(v.x); o.y = f2bf(v.y); o.z = f2bf(v.z); o.w = f2bf(v.w);
    *(ushort4*)(xb + i) = o;
}

// ---- prep: MbT[kk][o][i] = M(kk)[i][o] (bf16) -------------------------------
__global__ void k_transpose_M(const float* __restrict__ Mp, const float* __restrict__ Mm,
                              unsigned short* __restrict__ MbT) {
    __shared__ float tile[32][33];
    int kk = blockIdx.z;
    const float* src = ((kk < 24) ? Mp : Mm) + (size_t)((kk < 24) ? kk : kk - 24) * 65536;
    int i0 = blockIdx.x * 32, o0 = blockIdx.y * 32;
    int tx = threadIdx.x, ty = threadIdx.y;
    for (int j = 0; j < 4; ++j)
        tile[ty + j * 8][tx] = src[(i0 + ty + j * 8) * 256 + o0 + tx];
    __syncthreads();
    for (int j = 0; j < 4; ++j)
        MbT[(size_t)kk * 65536 + (o0 + ty + j * 8) * 256 + i0 + tx] = f2bf(tile[tx][ty + j * 8]);
}

// ---- prep: ToepA[kk][d][i][j] = sgn*phi[d*64+i-j][k]  (0 if t<0), bf16 -------
__global__ void k_prep_toep(const float* __restrict__ phi, unsigned short* __restrict__ ToepA) {
    int kk = blockIdx.x;   // 48
    int d  = blockIdx.y;   // 16
    int k = (kk < 24) ? kk : kk - 24;
    int row = threadIdx.x >> 2, c0 = (threadIdx.x & 3) * 16;
    unsigned short* dst = ToepA + ((size_t)kk * 16 + d) * 4096 + row * 64 + c0;
#pragma unroll
    for (int q = 0; q < 4; ++q) {
        ushort4 ov;
        unsigned short e[4];
#pragma unroll
        for (int ee = 0; ee < 4; ++ee) {
            int j = c0 + q * 4 + ee;
            int t = d * 64 + row - j;          // always <= 1023
            float v = 0.f;
            if (t >= 0) {
                v = phi[t * 24 + k];
                if (kk >= 24 && (t & 1)) v = -v;
            }
            e[ee] = f2bf(v);
        }
        ov.x = e[0]; ov.y = e[1]; ov.z = e[2]; ov.w = e[3];
        *(ushort4*)(dst + q * 4) = ov;
    }
}

// ---- stage 1: grid (8 m-tiles, 96 = 48kk x 2 o-halves, g batches), 256 thr ---
__global__ __launch_bounds__(256) void k_stage1(const unsigned short* __restrict__ xb0,
                                                const unsigned short* __restrict__ MbT,
                                                unsigned short* __restrict__ Z) {
    __shared__ unsigned short Al[128 * 40];
    __shared__ unsigned short Bl[128 * 40];
    int tid = threadIdx.x, lane = tid & 63, w = tid >> 6;
    int wm = w >> 1, wn = w & 1;
    int m0 = blockIdx.x * 128;
    int kk = blockIdx.y >> 1;
    int o0 = (blockIdx.y & 1) * 128;
    int b  = blockIdx.z;
    const unsigned short* xb_b = xb0 + (size_t)b * 262144;
    unsigned short* Zb = Z + (size_t)b * ZB_;
    const unsigned short* Bsrc = MbT + (size_t)kk * 65536;
    int l16 = lane & 15, kofs = (lane >> 4) * 8;

    f32x4 acc[4][4];
    for (int i = 0; i < 4; ++i)
        for (int j = 0; j < 4; ++j) {
            acc[i][j][0] = 0.f; acc[i][j][1] = 0.f; acc[i][j][2] = 0.f; acc[i][j][3] = 0.f;
        }

    int row = tid >> 1, half = tid & 1;
    const unsigned short* asrc = xb_b + (m0 + row) * 256 + half * 16;
    const unsigned short* bsrc = Bsrc + (o0 + row) * 256 + half * 16;
    uint4 va0 = *(const uint4*)(asrc);
    uint4 va1 = *(const uint4*)(asrc + 8);
    uint4 vb0 = *(const uint4*)(bsrc);
    uint4 vb1 = *(const uint4*)(bsrc + 8);

    for (int ko = 0; ko < 8; ++ko) {
        __syncthreads();
        *(uint4*)(Al + row * 40 + half * 16)     = va0;
        *(uint4*)(Al + row * 40 + half * 16 + 8) = va1;
        *(uint4*)(Bl + row * 40 + half * 16)     = vb0;
        *(uint4*)(Bl + row * 40 + half * 16 + 8) = vb1;
        __syncthreads();
        if (ko < 7) {
            va0 = *(const uint4*)(asrc + (ko + 1) * 32);
            va1 = *(const uint4*)(asrc + (ko + 1) * 32 + 8);
            vb0 = *(const uint4*)(bsrc + (ko + 1) * 32);
            vb1 = *(const uint4*)(bsrc + (ko + 1) * 32 + 8);
        }
        bf16x8 af[4], bfv[4];
        for (int mi = 0; mi < 4; ++mi)
            af[mi] = *(const bf16x8*)(Al + (wm * 64 + mi * 16 + l16) * 40 + kofs);
        for (int ni = 0; ni < 4; ++ni)
            bfv[ni] = *(const bf16x8*)(Bl + (wn * 64 + ni * 16 + l16) * 40 + kofs);
        for (int mi = 0; mi < 4; ++mi)
            for (int ni = 0; ni < 4; ++ni)
                acc[mi][ni] = __builtin_amdgcn_mfma_f32_16x16x32_bf16(af[mi], bfv[ni], acc[mi][ni], 0, 0, 0);
    }

    int r4 = (lane >> 4) * 4;
    for (int mi = 0; mi < 4; ++mi) {
        int sbase = m0 + wm * 64 + mi * 16 + r4;
        for (int ni = 0; ni < 4; ++ni) {
            int o = o0 + wn * 64 + ni * 16 + l16;
            ushort4 pk;
            pk.x = f2bf(acc[mi][ni][0]); pk.y = f2bf(acc[mi][ni][1]);
            pk.z = f2bf(acc[mi][ni][2]); pk.w = f2bf(acc[mi][ni][3]);
            *(ushort4*)(Zb + (size_t)kk * 262144 + (size_t)o * 1024 + sbase) = pk;
        }
    }
}

// ---- stage 2: grid (8 diag-pairs, 2 o-tiles x g batches, kg), 256 thr --------
// Block pr handles l-tiles {pr, 15-pr}: exactly 17 s-chunks -> uniform work.
__global__ __launch_bounds__(256) void k_stage2(const unsigned short* __restrict__ Z,
                                                const unsigned short* __restrict__ ToepA,
                                                float* __restrict__ partial, int kkpg) {
    __shared__ unsigned short Al[64 * 72];   // [64 l][64 s] pad->72
    __shared__ unsigned short Zl[128 * 72];  // [128 o][64 s] pad->72
    int tid = threadIdx.x, lane = tid & 63, w = tid >> 6;
    int wm = w >> 1, wn = w & 1;
    int pr = blockIdx.x;
    int o0 = (blockIdx.y & 1) * 128;
    int b  = blockIdx.y >> 1;
    int kgi = blockIdx.z;
    int kk0 = kgi * kkpg;
    int l16 = lane & 15, kofs = (lane >> 4) * 8;
    int r0 = tid >> 3, c8 = (tid & 7) * 8;

    const unsigned short* Zb = Z + (size_t)b * ZB_;
    float* pb = partial + ((size_t)b * gridDim.z + kgi) * 262144;

    for (int half = 0; half < 2; ++half) {
        int lb = half ? (15 - pr) : pr;
        int l0 = lb * 64;
        int nch = lb + 1;
        int total = kkpg * nch;

        f32x4 acc[2][4];
        for (int i = 0; i < 2; ++i)
            for (int j = 0; j < 4; ++j) {
                acc[i][j][0] = 0.f; acc[i][j][1] = 0.f; acc[i][j][2] = 0.f; acc[i][j][3] = 0.f;
            }

        uint4 zv[4], av[2];
        {   // preload chunk 0: kkx=0, sc=0, d=lb
#pragma unroll
            for (int it = 0; it < 4; ++it)
                zv[it] = *(const uint4*)(Zb + (size_t)kk0 * 262144 + (size_t)(o0 + it * 32 + r0) * 1024 + c8);
#pragma unroll
            for (int it = 0; it < 2; ++it)
                av[it] = *(const uint4*)(ToepA + ((size_t)kk0 * 16 + lb) * 4096 + (it * 32 + r0) * 64 + c8);
        }

        int sc = 0, kkx = 0;
        for (int j = 0; j < total; ++j) {
            __syncthreads();
#pragma unroll
            for (int it = 0; it < 4; ++it)
                *(uint4*)(Zl + (it * 32 + r0) * 72 + c8) = zv[it];
#pragma unroll
            for (int it = 0; it < 2; ++it)
                *(uint4*)(Al + (it * 32 + r0) * 72 + c8) = av[it];
            __syncthreads();

            int scn = sc + 1, kkn = kkx;
            if (scn == nch) { scn = 0; kkn = kkx + 1; }
            if (j + 1 < total) {   // prefetch next chunk (overlaps MFMA below)
                int kka = kk0 + kkn, d = lb - scn;
#pragma unroll
                for (int it = 0; it < 4; ++it)
                    zv[it] = *(const uint4*)(Zb + (size_t)kka * 262144 + (size_t)(o0 + it * 32 + r0) * 1024 + scn * 64 + c8);
#pragma unroll
                for (int it = 0; it < 2; ++it)
                    av[it] = *(const uint4*)(ToepA + ((size_t)kka * 16 + d) * 4096 + (it * 32 + r0) * 64 + c8);
            }

#pragma unroll
            for (int ks = 0; ks < 2; ++ks) {
                int ko = ks * 32 + kofs;
                bf16x8 af[2], bfv[4];
                for (int mi = 0; mi < 2; ++mi)
                    af[mi] = *(const bf16x8*)(Al + (wm * 32 + mi * 16 + l16) * 72 + ko);
                for (int ni = 0; ni < 4; ++ni)
                    bfv[ni] = *(const bf16x8*)(Zl + (wn * 64 + ni * 16 + l16) * 72 + ko);
                for (int mi = 0; mi < 2; ++mi)
                    for (int ni = 0; ni < 4; ++ni)
                        acc[mi][ni] = __builtin_amdgcn_mfma_f32_16x16x32_bf16(af[mi], bfv[ni], acc[mi][ni], 0, 0, 0);
            }
            sc = scn; kkx = kkn;
        }

        int r4 = (lane >> 4) * 4;
        for (int mi = 0; mi < 2; ++mi) {
            int l = l0 + wm * 32 + mi * 16 + r4;
            for (int ni = 0; ni < 4; ++ni) {
                int o = o0 + wn * 64 + ni * 16 + l16;
                float* dst = pb + (size_t)l * 256 + o;
                dst[0]   = acc[mi][ni][0];
                dst[256] = acc[mi][ni][1];
                dst[512] = acc[mi][ni][2];
                dst[768] = acc[mi][ni][3];
            }
        }
    }
}

// ---- reduce: out[b][l][o] = sum_kg partial[b][kg][l][o] ----------------------
__global__ void k_reduce(const float* __restrict__ partial, float* __restrict__ outg, int kg) {
    const float* pb = partial + (size_t)blockIdx.y * kg * 262144;
    int i = (blockIdx.x * 256 + threadIdx.x) * 4;
    float4 s = *(const float4*)(pb + i);
    for (int kgi = 1; kgi < kg; ++kgi) {
        float4 v = *(const float4*)(pb + (size_t)kgi * 262144 + i);
        s.x += v.x; s.y += v.y; s.z += v.z; s.w += v.w;
    }
    *(float4*)(outg + (size_t)blockIdx.y * 262144 + i) = s;
}

extern "C" void kernel_launch(void* const* d_in, const int* in_sizes, int n_in,
                              void* d_out, int out_size, void* d_ws, size_t ws_size,
                              hipStream_t stream) {
    const float* x   = (const float*)d_in[0];   // [4,1024,256]
    const float* phi = (const float*)d_in[1];   // [1024,24]
    const float* Mp  = (const float*)d_in[2];   // [24,256,256]
    const float* Mm  = (const float*)d_in[3];   // [24,256,256]
    float* out = (float*)d_out;                 // [4,1024,256]

    char* ws = (char*)d_ws;
    unsigned short* xb    = (unsigned short*)(ws);             // 2,097,152 B
    unsigned short* MbT   = (unsigned short*)(ws + 2097152);   // 6,291,456 B
    unsigned short* ToepA = (unsigned short*)(ws + 8388608);   // 6,291,456 B
    unsigned short* Zbuf  = (unsigned short*)(ws + 14680064);  // g * 25,165,824 B
    const size_t fixed = 14680064;

    // pick batch-group size g and split-K kg to fit ws_size
    int g = 4, kg = 12;
    auto need = [&](int gg, int kk) {
        return fixed + (size_t)gg * 25165824 + (size_t)gg * (size_t)kk * 1048576;
    };
    if (need(4, 12) > ws_size) {
        g = 2;
        if (need(2, 12) > ws_size) {
            g = 1;
            if (need(1, 12) > ws_size) kg = 6;   // 46,137,344 B total
        }
    }
    float* partial = (float*)(ws + fixed + (size_t)g * 25165824);

    k_prep_x<<<dim3(1024), dim3(256), 0, stream>>>(x, xb);
    k_transpose_M<<<dim3(8, 8, 48), dim3(32, 8), 0, stream>>>(Mp, Mm, MbT);
    k_prep_toep<<<dim3(48, 16), dim3(256), 0, stream>>>(phi, ToepA);

    for (int b0 = 0; b0 < 4; b0 += g) {
        k_stage1<<<dim3(8, 96, g), dim3(256), 0, stream>>>(xb + (size_t)b0 * 262144, MbT, Zbuf);
        k_stage2<<<dim3(8, 2 * g, kg), dim3(256), 0, stream>>>(Zbuf, ToepA, partial, 48 / kg);
        k_reduce<<<dim3(256, g), dim3(256), 0, stream>>>(partial, out + (size_t)b0 * 262144, kg);
    }
}